// Round 7
// baseline (103.427 us; speedup 1.0000x reference)
//
#include <hip/hip_runtime.h>
#include <stdint.h>

// y[n,i] = relu(b[idx[n],i] + sum_o w[idx[n],i,o] * x[n,o])
// B=8192, 64 models, 256x256 fp32.
// R7: LDS-free MFMA. After a 2-barrier compaction scan, each wave loads its
// A/B fragments DIRECTLY from global (x rows gathered via rid, w rows are
// naturally K-major) with in-register fp32->bf16 cvt. No tile staging, no
// ds_read/ds_write, zero LDS bank conflicts, no barriers in the MFMA phase.
// Grid 512 = 64 models x 2 sample-tiles x 4 n-tiles; bid%8 == model%8 so all
// 8 blocks of a model share one XCD (w dup reads hit 4MB L2; 2 blocks/CU).

#define N_MODELS 64
#define IN_F     256
#define OUT_F    256
#define BM       128

typedef __bf16 bf16x8 __attribute__((ext_vector_type(8)));
typedef float  f32x4  __attribute__((ext_vector_type(4)));

__device__ __forceinline__ bf16x8 cvt8(float4 a, float4 b) {
  bf16x8 o;                       // v_cvt_pk_bf16_f32 x4
  o[0] = (__bf16)a.x; o[1] = (__bf16)a.y; o[2] = (__bf16)a.z; o[3] = (__bf16)a.w;
  o[4] = (__bf16)b.x; o[5] = (__bf16)b.y; o[6] = (__bf16)b.z; o[7] = (__bf16)b.w;
  return o;
}

__global__ __launch_bounds__(512) void fused_kernel(
    const float* __restrict__ x, const int* __restrict__ idxs,
    const float* __restrict__ w, const float* __restrict__ bias_g,
    float* __restrict__ out) {
  // bid bits: [2:0]=model low (XCD id), [4:3]=n-tile, [5]=sample-tile,
  //           [8:6]=model high  -> all blocks of a model on one XCD.
  const int bid   = blockIdx.x;
  const int model = (bid & 7) | ((bid >> 6) << 3);
  const int i0    = ((bid >> 3) & 3) * 64;
  const int tile  = (bid >> 5) & 1;
  const int t     = threadIdx.x;
  const int lane  = t & 63;
  const int wv    = t >> 6;            // 0..7

  __shared__ int rid[BM];
  __shared__ int wsum[8];

  const int wm   = (wv & 3) * 32;      // 4 sample-waves x 2 n-waves
  const int wn   = (wv >> 2) * 32;
  const int col  = lane & 15;
  const int quad = lane >> 4;

  // bias early (in flight under the scan)
  const float* bp = bias_g + model * OUT_F + i0 + wn + col;
  const float bv0 = bp[0];
  const float bv1 = bp[16];

  if (t < BM) rid[t] = 0;              // pad rows -> x row 0 (never stored)

  // ---- compaction scan: thread t owns idxs[16t..16t+15] ----
  const int4* ip = (const int4*)idxs + t * 4;
  int4 iv[4];
#pragma unroll
  for (int j = 0; j < 4; ++j) iv[j] = ip[j];
  int cnt = 0;
#pragma unroll
  for (int j = 0; j < 4; ++j) {
    int4 v = iv[j];
    cnt += (v.x == model) + (v.y == model) + (v.z == model) + (v.w == model);
  }
  int inc = cnt;
#pragma unroll
  for (int d = 1; d < 64; d <<= 1) {
    int s = __shfl_up(inc, d);
    if (lane >= d) inc += s;
  }
  if (lane == 63) wsum[wv] = inc;
  __syncthreads();                     // rid init + wsum ready
  int wpre = 0, total = 0;
#pragma unroll
  for (int j = 0; j < 8; ++j) {
    int s = wsum[j];
    total += s;
    if (j < wv) wpre += s;
  }
  const int start = tile * BM;
  int off = wpre + inc - cnt - start;
#pragma unroll
  for (int j = 0; j < 4; ++j) {
    int4 v = iv[j];
    int n0 = t * 16 + j * 4;
    if (v.x == model) { if ((unsigned)off < BM) rid[off] = n0 + 0; ++off; }
    if (v.y == model) { if ((unsigned)off < BM) rid[off] = n0 + 1; ++off; }
    if (v.z == model) { if ((unsigned)off < BM) rid[off] = n0 + 2; ++off; }
    if (v.w == model) { if ((unsigned)off < BM) rid[off] = n0 + 3; ++off; }
  }
  __syncthreads();                     // rid ready; LAST barrier
  if (start >= total) return;          // empty blocks exit before any w read
  const int rows = min(total - start, BM);

  // ---- fragment base pointers (A gathered by rid, B = w rows) ----
  const float* pA[2];
#pragma unroll
  for (int mt = 0; mt < 2; ++mt)
    pA[mt] = x + (size_t)rid[wm + mt * 16 + col] * IN_F + quad * 8;
  const float* pB[2];
#pragma unroll
  for (int nt = 0; nt < 2; ++nt)
    pB[nt] = w + (size_t)model * (IN_F * OUT_F)
               + (size_t)(i0 + wn + nt * 16 + col) * IN_F + quad * 8;

  f32x4 acc[2][2];                     // bias folded into acc init
  acc[0][0] = (f32x4){bv0, bv0, bv0, bv0};
  acc[1][0] = acc[0][0];
  acc[0][1] = (f32x4){bv1, bv1, bv1, bv1};
  acc[1][1] = acc[0][1];

  // ---- MFMA: 8 k-steps, fragments straight from global, no barriers ----
#pragma unroll
  for (int ks = 0; ks < 8; ++ks) {
    bf16x8 af[2], bfr[2];
#pragma unroll
    for (int mt = 0; mt < 2; ++mt) {
      float4 a0 = *(const float4*)(pA[mt] + ks * 32);
      float4 a1 = *(const float4*)(pA[mt] + ks * 32 + 4);
      af[mt] = cvt8(a0, a1);
    }
#pragma unroll
    for (int nt = 0; nt < 2; ++nt) {
      float4 b0 = *(const float4*)(pB[nt] + ks * 32);
      float4 b1 = *(const float4*)(pB[nt] + ks * 32 + 4);
      bfr[nt] = cvt8(b0, b1);
    }
#pragma unroll
    for (int mt = 0; mt < 2; ++mt)
#pragma unroll
      for (int nt = 0; nt < 2; ++nt)
        acc[mt][nt] = __builtin_amdgcn_mfma_f32_16x16x32_bf16(
            af[mt], bfr[nt], acc[mt][nt], 0, 0, 0);
  }

  // ---- epilogue: relu + scatter by sample id ----
#pragma unroll
  for (int mt = 0; mt < 2; ++mt) {
#pragma unroll
    for (int reg = 0; reg < 4; ++reg) {
      const int mm = wm + mt * 16 + quad * 4 + reg;   // C/D: row = quad*4+reg
      if (mm < rows) {
        const int s = rid[mm];
        float* orow = out + (size_t)s * OUT_F + i0 + wn + col;
        orow[0]  = fmaxf(acc[mt][0][reg], 0.0f);
        orow[16] = fmaxf(acc[mt][1][reg], 0.0f);
      }
    }
  }
}

extern "C" void kernel_launch(void* const* d_in, const int* in_sizes, int n_in,
                              void* d_out, int out_size, void* d_ws, size_t ws_size,
                              hipStream_t stream) {
  const float* x    = (const float*)d_in[0];
  const int*   idxs = (const int*)d_in[1];
  const float* w    = (const float*)d_in[2];
  const float* b    = (const float*)d_in[3];
  float* out = (float*)d_out;
  (void)d_ws; (void)ws_size;

  fused_kernel<<<512, 512, 0, stream>>>(x, idxs, w, b, out);
}

// Round 8
// 86.814 us; speedup vs baseline: 1.1914x; 1.1914x over previous
//
#include <hip/hip_runtime.h>
#include <stdint.h>

// y[n,i] = relu(b[idx[n],i] + sum_o w[idx[n],i,o] * x[n,o])
// B=8192, 64 models, 256x256 fp32. R8 = R4 structure with ONLY the staging
// addressing changed (clean A/B vs R4's 85.8us):
//  - linearized coalesced staging: thread t handles float4 index t+k*1024 of
//    the 8192-f4 tile -> each wave load instr spans a contiguous 1KB (16
//    fully-used 64B lines, vs 64 quarter-used lines in R4);
//  - LDS writes: one wave instr writes one full 512B LDS row (b64 stores,
//    structural minimum, kills the 1.08M bank-conflict cycles);
//  - scan loads linearized likewise. Scan stays 16-way parallel, no flags.

#define N_MODELS 64
#define IN_F     256
#define OUT_F    256
#define BM       128
#define BN       128
#define PK       264   // LDS pitch bf16 (256+8); frag ds_read_b128 at
                       // structural-minimum bank spread; rows 16B-aligned

typedef __bf16 bf16x4 __attribute__((ext_vector_type(4)));
typedef __bf16 bf16x8 __attribute__((ext_vector_type(8)));
typedef float  f32x4  __attribute__((ext_vector_type(4)));

__device__ __forceinline__ bf16x4 pack4(float4 a) {
  bf16x4 o;                  // 2x v_cvt_pk_bf16_f32
  o[0] = (__bf16)a.x; o[1] = (__bf16)a.y; o[2] = (__bf16)a.z; o[3] = (__bf16)a.w;
  return o;
}

__global__ __launch_bounds__(1024) void fused_kernel(
    const float* __restrict__ x, const int* __restrict__ idxs,
    const float* __restrict__ w, const float* __restrict__ bias_g,
    float* __restrict__ out) {
  const int model = blockIdx.x >> 2;
  const int tile  = (blockIdx.x >> 1) & 1;
  const int i0    = (blockIdx.x & 1) * BN;
  const int t     = threadIdx.x;
  const int lane  = t & 63;
  const int wv    = t >> 6;          // 0..15

  __shared__ unsigned short a_lds[BM][PK];  // gathered x rows, bf16
  __shared__ unsigned short b_lds[BN][PK];  // w rows, bf16
  __shared__ int rid[BM];
  __shared__ int wsum[16];

  // ---- idx loads first (coalesced: contiguous 1KB per wave instr) ----
  const int4* ip = (const int4*)idxs;
  int4 iv0 = ip[t];                  // idxs[4t .. 4t+3]
  int4 iv1 = ip[t + 1024];           // idxs[4096+4t .. 4096+4t+3]

  // ---- w staging, tile0 blocks (before the scan; they never early-exit
  //      except for the impossible total==0 case) ----
  const float4* wbase = (const float4*)(w + (size_t)model * (IN_F * OUT_F)
                                          + (size_t)i0 * IN_F);
  if (tile == 0) {
    float4 tw[8];
#pragma unroll
    for (int k = 0; k < 8; ++k) tw[k] = wbase[t + k * 1024];   // 8 in flight
#pragma unroll
    for (int k = 0; k < 8; ++k) {
      const int f4 = t + k * 1024;   // row = f4>>6; one wave = one LDS row
      *(bf16x4*)&b_lds[f4 >> 6][(f4 & 63) * 4] = pack4(tw[k]);
    }
  }

  if (t < BM) rid[t] = 0;            // pads -> x row 0 (never stored)

  // ---- phase 1: 16-way parallel compaction scan ----
  int cnt = (iv0.x == model) + (iv0.y == model) + (iv0.z == model) + (iv0.w == model)
          + (iv1.x == model) + (iv1.y == model) + (iv1.z == model) + (iv1.w == model);
  int inc = cnt;
#pragma unroll
  for (int d = 1; d < 64; d <<= 1) {
    int s = __shfl_up(inc, d);
    if (lane >= d) inc += s;
  }
  if (lane == 63) wsum[wv] = inc;
  __syncthreads();                   // rid init + wsum ready
  int wpre = 0, total = 0;
#pragma unroll
  for (int j = 0; j < 16; ++j) {
    int s = wsum[j];
    total += s;
    if (j < wv) wpre += s;
  }
  const int start = tile * BM;
  if (start >= total) return;        // block-uniform early exit
  const int rows = min(total - start, BM);

  int off = wpre + inc - cnt - start;
  {
    const int n0 = t * 4;            // iv0 = idxs[4t..], iv1 = idxs[4096+4t..]
    if (iv0.x == model) { if ((unsigned)off < BM) rid[off] = n0 + 0; ++off; }
    if (iv0.y == model) { if ((unsigned)off < BM) rid[off] = n0 + 1; ++off; }
    if (iv0.z == model) { if ((unsigned)off < BM) rid[off] = n0 + 2; ++off; }
    if (iv0.w == model) { if ((unsigned)off < BM) rid[off] = n0 + 3; ++off; }
    if (iv1.x == model) { if ((unsigned)off < BM) rid[off] = n0 + 4096; ++off; }
    if (iv1.y == model) { if ((unsigned)off < BM) rid[off] = n0 + 4097; ++off; }
    if (iv1.z == model) { if ((unsigned)off < BM) rid[off] = n0 + 4098; ++off; }
    if (iv1.w == model) { if ((unsigned)off < BM) rid[off] = n0 + 4099; ++off; }
  }
  __syncthreads();                   // rid ready

  // ---- w staging for tile1 (after proving non-empty) ----
  if (tile == 1) {
    float4 tw[8];
#pragma unroll
    for (int k = 0; k < 8; ++k) tw[k] = wbase[t + k * 1024];
#pragma unroll
    for (int k = 0; k < 8; ++k) {
      const int f4 = t + k * 1024;
      *(bf16x4*)&b_lds[f4 >> 6][(f4 & 63) * 4] = pack4(tw[k]);
    }
  }

  // ---- x staging: gathered rows, coalesced (one row per wave instr) ----
  {
    int sr[8];
#pragma unroll
    for (int k = 0; k < 8; ++k)      // wave-uniform broadcast reads of rid
      sr[k] = rid[(t + k * 1024) >> 6];
    float4 tx[8];
#pragma unroll
    for (int k = 0; k < 8; ++k)      // contiguous 1KB per wave instr
      tx[k] = ((const float4*)(x + (size_t)sr[k] * IN_F))[(t + k * 1024) & 63];
#pragma unroll
    for (int k = 0; k < 8; ++k) {
      const int f4 = t + k * 1024;
      *(bf16x4*)&a_lds[f4 >> 6][(f4 & 63) * 4] = pack4(tx[k]);
    }
  }

  // bias (issued while staging drains)
  const int wm   = (wv & 3) * 32;    // 4x4 wave grid of 32x32 tiles
  const int wn   = (wv >> 2) * 32;
  const int col  = lane & 15;
  const int quad = lane >> 4;
  const float* bp = bias_g + model * OUT_F + i0 + wn + col;
  const float bv0 = bp[0];
  const float bv1 = bp[16];

  __syncthreads();                   // tiles ready; last barrier

  f32x4 acc[2][2];                   // bias folded into acc init
  acc[0][0] = (f32x4){bv0, bv0, bv0, bv0};
  acc[1][0] = acc[0][0];
  acc[0][1] = (f32x4){bv1, bv1, bv1, bv1};
  acc[1][1] = acc[0][1];

  // ---- phase 3: 8 k-steps x 4 MFMA per wave, zero barriers ----
#pragma unroll
  for (int ks = 0; ks < 8; ++ks) {
    bf16x8 af[2], bfr[2];
#pragma unroll
    for (int mt = 0; mt < 2; ++mt)
      af[mt] = *(const bf16x8*)&a_lds[wm + mt * 16 + col][ks * 32 + quad * 8];
#pragma unroll
    for (int nt = 0; nt < 2; ++nt)
      bfr[nt] = *(const bf16x8*)&b_lds[wn + nt * 16 + col][ks * 32 + quad * 8];
#pragma unroll
    for (int mt = 0; mt < 2; ++mt)
#pragma unroll
      for (int nt = 0; nt < 2; ++nt)
        acc[mt][nt] = __builtin_amdgcn_mfma_f32_16x16x32_bf16(
            af[mt], bfr[nt], acc[mt][nt], 0, 0, 0);
  }

  // ---- epilogue: relu + scatter by sample id ----
#pragma unroll
  for (int mt = 0; mt < 2; ++mt) {
#pragma unroll
    for (int reg = 0; reg < 4; ++reg) {
      const int mm = wm + mt * 16 + quad * 4 + reg;   // C/D: row = quad*4+reg
      if (mm < rows) {
        const int s = rid[mm];
        float* orow = out + (size_t)s * OUT_F + i0 + wn + col;
        orow[0]  = fmaxf(acc[0 + mt][0][reg], 0.0f);
        orow[16] = fmaxf(acc[0 + mt][1][reg], 0.0f);
      }
    }
  }
}

extern "C" void kernel_launch(void* const* d_in, const int* in_sizes, int n_in,
                              void* d_out, int out_size, void* d_ws, size_t ws_size,
                              hipStream_t stream) {
  const float* x    = (const float*)d_in[0];
  const int*   idxs = (const int*)d_in[1];
  const float* w    = (const float*)d_in[2];
  const float* b    = (const float*)d_in[3];
  float* out = (float*)d_out;
  (void)d_ws; (void)ws_size;

  fused_kernel<<<N_MODELS * 4, 1024, 0, stream>>>(x, idxs, w, b, out);
}